// Round 11
// baseline (806.602 us; speedup 1.0000x reference)
//
#include <hip/hip_runtime.h>
#include <cstdio>

#define BATCH 256
#define TSEQ  393
#define CH    128
#define FIN   3
#define TIN   800
#define KK    15
#define HID   150
#define NPAD  640      // interleaved gate dim: n = 4*j + gate, j<160 (j>=150 pad)
#define KPAD  160      // padded hidden dim for W_hh
#define NB    16       // batch rows per recurrence block
#define PHASE 131      // 3 phases x 131 = 393
#define SLOTSTRIDE (256*640)    // halves between slots: [256 b][640 n]
#define HSTR  170      // h row stride in halves (odd dword stride -> conflict-free, R10: 0 conflicts)
// LDS inflation: 43000 halves = 86000 B > 160KB/2 -> HW can place only ONE block
// per CU. R4-R10 post-mortem: launch_bounds(512,2)+11KB LDS let the dispatcher
// pack 2 recur blocks/CU => 1940cy/step of matrix-pipe load; every measured
// step time (3000-4400cy) is that load x ~1.6. Exclusive CU => ~1550cy/step.
#define LDSPAD 43000

typedef _Float16 half_t;
typedef __attribute__((ext_vector_type(8))) _Float16 h8v;
typedef __attribute__((ext_vector_type(4))) _Float16 h4v;
typedef __attribute__((ext_vector_type(4))) float f4v;

__device__ inline float hsig(float x){
  return __builtin_amdgcn_fmed3f(fmaf(0.2f, x, 0.5f), 0.f, 1.f);
}
__device__ inline float tanh_(float x){
  float e = __expf(2.f*x);
  return fmaf(-2.f, __builtin_amdgcn_rcpf(e + 1.f), 1.f);
}

// ================= setup: weight prep + conv fused (independent roles) =================
__global__ __launch_bounds__(256) void setup(const float* __restrict__ x,
    const float* __restrict__ conv_w, const float* __restrict__ conv_b,
    const float* __restrict__ wihf, const float* __restrict__ whhf,
    const float* __restrict__ bihf, const float* __restrict__ bhhf,
    const float* __restrict__ wihb, const float* __restrict__ whhb,
    const float* __restrict__ bihb, const float* __restrict__ bhhb,
    half_t* __restrict__ xseq, half_t* __restrict__ wih, half_t* __restrict__ whh,
    float* __restrict__ bsum){
  __shared__ float wl[CH*FIN*KK];
  __shared__ float xl[FIN][78];
  int bx = blockIdx.x, tid = threadIdx.x;
  if (bx < 3328){                       // conv1d+relu+maxpool2 -> xseq f16 [B][T][C]
    int b = bx & 255, t0 = (bx >> 8)*32;
    for (int i = tid; i < CH*FIN*KK; i += 256) wl[i] = conv_w[i];
    int p0 = 2*t0;
    for (int i = tid; i < FIN*78; i += 256){
      int f = i/78, q = i%78; int p = p0 + q;
      xl[f][q] = (p < TIN) ? x[((size_t)b*FIN + f)*TIN + p] : 0.f;
    }
    __syncthreads();
    int c = tid & 127, th = tid >> 7;
    float a0[16], a1[16];
    #pragma unroll
    for (int i=0;i<16;++i){ a0[i]=0.f; a1[i]=0.f; }
    #pragma unroll
    for (int f=0; f<FIN; ++f){
      float xv[46];
      #pragma unroll
      for (int q=0;q<46;++q) xv[q] = xl[f][th*32 + q];
      #pragma unroll
      for (int k=0;k<KK;++k){
        float ws = wl[c*FIN*KK + f*KK + k];
        #pragma unroll
        for (int i=0;i<16;++i){
          a0[i] = fmaf(xv[2*i+k],   ws, a0[i]);
          a1[i] = fmaf(xv[2*i+k+1], ws, a1[i]);
        }
      }
    }
    float bc = conv_b[c];
    #pragma unroll
    for (int i=0;i<16;++i){
      int t = t0 + th*16 + i;
      if (t < TSEQ){
        float v = fmaxf(fmaxf(a0[i], a1[i]) + bc, 0.f);
        xseq[((size_t)b*TSEQ + t)*CH + c] = (half_t)v;
      }
    }
    return;
  }
  bx -= 3328;
  if (bx < 640){                        // W_ih -> f16 gate-interleaved: n = 4j+g
    int i = bx*256 + tid;
    int c = i & 127; int n = (i >> 7) % NPAD; int d = i / (NPAD*CH);
    const float* src = d ? wihb : wihf;
    float v = 0.f;
    if (n < 600){ int j = n >> 2, g = n & 3; v = src[(g*HID + j)*CH + c]; }
    wih[i] = (half_t)v;
    return;
  }
  bx -= 640;
  if (bx < 800){                        // W_hh -> f16, canonical k cols
    int i = bx*256 + tid;
    int kc = i % KPAD; int n = (i / KPAD) % NPAD; int d = i / (NPAD*KPAD);
    const float* src = d ? whhb : whhf;
    float v = 0.f;
    if (n < 600 && kc < HID){ int j = n >> 2, g = n & 3; v = src[(g*HID + j)*HID + kc]; }
    whh[i] = (half_t)v;
    return;
  }
  { int i = (bx-800)*256 + tid;         // bias sum, interleaved
    if (i < 2*NPAD){
      int n = i % NPAD; int d = i / NPAD;
      float v = 0.f;
      if (n < 600){ int j = n >> 2, g = n & 3; int r = g*HID + j;
        v = d ? (bihb[r] + bhhb[r]) : (bihf[r] + bhhf[r]); }
      bsum[i] = v;
    }
  }
}

// ================= proj body (A=W_ih, B=x) =================
// D[n-rows][b-cols]: lane (b=ln&15, kg) holds n = tile*16 + kg*4 + r.
// pre layout: [d][slot][256 b][640 n] f16 (linear).
__device__ __forceinline__ void proj_body(const half_t* __restrict__ xseq,
    const half_t* __restrict__ wih, const float* __restrict__ bsum,
    half_t* __restrict__ pre, int off, int nproj, int idx){
  int bt4 = idx & 3; int rest = idx >> 2;
  int s = rest % nproj; int d = rest / nproj;
  int sg = s + off;
  int t = d ? (TSEQ-1 - sg) : sg;
  int tid = threadIdx.x, wv = tid >> 6, ln = tid & 63;
  int m = ln & 15, kg = ln >> 4;
  half_t* pslot = pre + ((size_t)d*PHASE + s)*SLOTSTRIDE;
  #pragma unroll
  for (int i = 0; i < 5; ++i){
    int nt = (wv*5 + i)*16;
    h8v bfr[4];
    #pragma unroll
    for (int ks = 0; ks < 4; ++ks)
      bfr[ks] = *(const h8v*)(wih + ((size_t)d*NPAD + nt + m)*CH + ks*32 + kg*8);
    f4v bs4 = *(const f4v*)(bsum + d*NPAD + nt + kg*4);
    #pragma unroll
    for (int ms = 0; ms < 4; ++ms){
      int b = bt4*64 + ms*16 + m;
      h8v ax[4];
      #pragma unroll
      for (int ks = 0; ks < 4; ++ks)
        ax[ks] = *(const h8v*)(xseq + ((size_t)b*TSEQ + t)*CH + ks*32 + kg*8);
      f4v acc = bs4;
      #pragma unroll
      for (int ks = 0; ks < 4; ++ks)
        acc = __builtin_amdgcn_mfma_f32_16x16x32_f16(bfr[ks], ax[ks], acc, 0, 0, 0);
      h4v hv = {(half_t)acc[0], (half_t)acc[1], (half_t)acc[2], (half_t)acc[3]};
      *(h4v*)(pslot + (size_t)b*640 + nt + kg*4) = hv;
    }
  }
}

__global__ __launch_bounds__(512) void proj_kernel(const half_t* __restrict__ xseq,
    const half_t* __restrict__ wih, const float* __restrict__ bsum,
    half_t* __restrict__ pre, int off, int nproj){
  proj_body(xseq, wih, bsum, pre, off, nproj, blockIdx.x);
}

// ================= recurrence + looping proj workers =================
#define PIN4(R0,R1,R2,R3, V) asm volatile( \
  "v_accvgpr_write_b32 " R0 ", %0\n\t" \
  "v_accvgpr_write_b32 " R1 ", %1\n\t" \
  "v_accvgpr_write_b32 " R2 ", %2\n\t" \
  "v_accvgpr_write_b32 " R3 ", %3" \
  :: "v"(V[0]), "v"(V[1]), "v"(V[2]), "v"(V[3]) : R0, R1, R2, R3)

#define LP(I,KS, R0,R1,R2,R3) { \
  h8v w_ = *(const h8v*)(whh + ((size_t)d*NPAD + ((wv*5+(I))*16+m))*KPAD + (KS)*32 + kg*8); \
  f4v wf_; __builtin_memcpy(&wf_, &w_, 16); \
  PIN4(R0,R1,R2,R3, wf_); }

#define ACLOBS "a0","a1","a2","a3","a4","a5","a6","a7","a8","a9",\
"a10","a11","a12","a13","a14","a15","a16","a17","a18","a19",\
"a20","a21","a22","a23","a24","a25","a26","a27","a28","a29",\
"a30","a31","a32","a33","a34","a35","a36","a37","a38","a39",\
"a40","a41","a42","a43","a44","a45","a46","a47","a48","a49",\
"a50","a51","a52","a53","a54","a55","a56","a57","a58","a59",\
"a60","a61","a62","a63","a64","a65","a66","a67","a68","a69",\
"a70","a71","a72","a73","a74","a75","a76","a77","a78","a79",\
"a80","a81","a82","a83","a84","a85","a86","a87","a88","a89",\
"a90","a91","a92","a93","a94","a95","a96","a97","a98","a99"

__global__ __launch_bounds__(512, 2) void recur_fused(
    const half_t* __restrict__ preR, const half_t* __restrict__ whh,
    float* __restrict__ pooled, float* __restrict__ stateC, half_t* __restrict__ stateH,
    int first, int last,
    const half_t* __restrict__ xseq, const half_t* __restrict__ wih,
    const float* __restrict__ bsum, half_t* __restrict__ preW,
    int off_next, int nproj){
  // 86KB static LDS => exactly one block per CU (exclusive matrix pipe).
  __shared__ __align__(16) half_t hbuf[LDSPAD];     // first 2*NB*HSTR halves used

  if (blockIdx.x >= 32){
    // proj worker: loop over this phase's 8*nproj units, 224 workers (1/CU)
    for (int u = blockIdx.x - 32; u < 8*nproj; u += 224)
      proj_body(xseq, wih, bsum, preW, off_next, nproj, u);
    return;
  }

  int tid = threadIdx.x, wv = tid >> 6, ln = tid & 63;
  int m = ln & 15, kg = ln >> 4;
  int bl = m;                       // batch-local (D col)
  int bt = blockIdx.x & 15, d = blockIdx.x >> 4;
  int b0 = bt*NB;
  int blk = d*16 + bt;

  // pin W_hh A-fragments into physical AGPRs: frag(T,ks) -> a[20T+4ks .. +3]
  LP(0,0,"a0","a1","a2","a3")    LP(0,1,"a4","a5","a6","a7")    LP(0,2,"a8","a9","a10","a11")
  LP(0,3,"a12","a13","a14","a15") LP(0,4,"a16","a17","a18","a19")
  LP(1,0,"a20","a21","a22","a23") LP(1,1,"a24","a25","a26","a27") LP(1,2,"a28","a29","a30","a31")
  LP(1,3,"a32","a33","a34","a35") LP(1,4,"a36","a37","a38","a39")
  LP(2,0,"a40","a41","a42","a43") LP(2,1,"a44","a45","a46","a47") LP(2,2,"a48","a49","a50","a51")
  LP(2,3,"a52","a53","a54","a55") LP(2,4,"a56","a57","a58","a59")
  LP(3,0,"a60","a61","a62","a63") LP(3,1,"a64","a65","a66","a67") LP(3,2,"a68","a69","a70","a71")
  LP(3,3,"a72","a73","a74","a75") LP(3,4,"a76","a77","a78","a79")
  LP(4,0,"a80","a81","a82","a83") LP(4,1,"a84","a85","a86","a87") LP(4,2,"a88","a89","a90","a91")
  LP(4,3,"a92","a93","a94","a95") LP(4,4,"a96","a97","a98","a99")

  // lane identity: cells j = (wv*5+T)*4 + kg, batch bl
  int jb = wv*20 + kg;              // + T*4

  float c_reg[5], hm_reg[5];
  if (first){
    for (int i = tid; i < 2*NB*HSTR; i += 512) hbuf[i] = (half_t)0.f;
    #pragma unroll
    for (int T = 0; T < 5; ++T){ c_reg[T] = 0.f; hm_reg[T] = -1e30f; }
  } else {
    for (int i = tid; i < NB*HSTR; i += 512) hbuf[i] = stateH[(size_t)blk*NB*HSTR + i];
    for (int i = tid; i < NB*HSTR; i += 512) hbuf[NB*HSTR + i] = (half_t)0.f;
    const float* sc = stateC + ((size_t)blk*512 + tid)*10;
    #pragma unroll
    for (int T = 0; T < 5; ++T){ c_reg[T] = sc[T]; hm_reg[T] = sc[5+T]; }
  }
  __syncthreads();

  const half_t* pb = preR + (size_t)d*PHASE*SLOTSTRIDE + (size_t)b0*640;
  int pofl = bl*640 + wv*80 + kg*4;   // + T*16

  // depth-2 register prefetch pipeline
  h4v curp[5], nA[5];
  #pragma unroll
  for (int T = 0; T < 5; ++T) curp[T] = *(const h4v*)(pb + pofl + T*16);
  {
    const half_t* p1 = pb + (size_t)SLOTSTRIDE;
    #pragma unroll
    for (int T = 0; T < 5; ++T) nA[T] = *(const h4v*)(p1 + pofl + T*16);
  }

  int p = 0;
  #pragma unroll 1
  for (int s = 0; s < PHASE; ++s){
    int s2 = (s+2 < PHASE) ? s+2 : PHASE-1;
    const half_t* p2 = pb + (size_t)s2*SLOTSTRIDE;
    h4v nB[5];
    #pragma unroll
    for (int T = 0; T < 5; ++T) nB[T] = *(const h4v*)(p2 + pofl + T*16);

    // B fragments from h buffer p: lane bl reads h[bl][k-chunks]
    const half_t* hrd = hbuf + p*NB*HSTR + bl*HSTR;
    h8v ah0 = *(const h8v*)(hrd + 0*32 + kg*8);
    h8v ah1 = *(const h8v*)(hrd + 1*32 + kg*8);
    h8v ah2 = *(const h8v*)(hrd + 2*32 + kg*8);
    h8v ah3 = *(const h8v*)(hrd + 3*32 + kg*8);
    h8v ah4 = *(const h8v*)(hrd + 4*32 + kg*8);

    // acc preloaded with pre (C operand)
    f4v acc0 = {(float)curp[0][0], (float)curp[0][1], (float)curp[0][2], (float)curp[0][3]};
    f4v acc1 = {(float)curp[1][0], (float)curp[1][1], (float)curp[1][2], (float)curp[1][3]};
    f4v acc2 = {(float)curp[2][0], (float)curp[2][1], (float)curp[2][2], (float)curp[2][3]};
    f4v acc3 = {(float)curp[3][0], (float)curp[3][1], (float)curp[3][2], (float)curp[3][3]};
    f4v acc4 = {(float)curp[4][0], (float)curp[4][1], (float)curp[4][2], (float)curp[4][3]};

    // 25 MFMAs: A = W (AGPR literal), B = h, C/D = acc. ks-major, 5 chains.
    asm volatile(
      "s_nop 1\n\t"
      "v_mfma_f32_16x16x32_f16 %0, a[0:3], %5, %0\n\t"
      "v_mfma_f32_16x16x32_f16 %1, a[20:23], %5, %1\n\t"
      "v_mfma_f32_16x16x32_f16 %2, a[40:43], %5, %2\n\t"
      "v_mfma_f32_16x16x32_f16 %3, a[60:63], %5, %3\n\t"
      "v_mfma_f32_16x16x32_f16 %4, a[80:83], %5, %4\n\t"
      "v_mfma_f32_16x16x32_f16 %0, a[4:7], %6, %0\n\t"
      "v_mfma_f32_16x16x32_f16 %1, a[24:27], %6, %1\n\t"
      "v_mfma_f32_16x16x32_f16 %2, a[44:47], %6, %2\n\t"
      "v_mfma_f32_16x16x32_f16 %3, a[64:67], %6, %3\n\t"
      "v_mfma_f32_16x16x32_f16 %4, a[84:87], %6, %4\n\t"
      "v_mfma_f32_16x16x32_f16 %0, a[8:11], %7, %0\n\t"
      "v_mfma_f32_16x16x32_f16 %1, a[28:31], %7, %1\n\t"
      "v_mfma_f32_16x16x32_f16 %2, a[48:51], %7, %2\n\t"
      "v_mfma_f32_16x16x32_f16 %3, a[68:71], %7, %3\n\t"
      "v_mfma_f32_16x16x32_f16 %4, a[88:91], %7, %4\n\t"
      "v_mfma_f32_16x16x32_f16 %0, a[12:15], %8, %0\n\t"
      "v_mfma_f32_16x16x32_f16 %1, a[32:35], %8, %1\n\t"
      "v_mfma_f32_16x16x32_f16 %2, a[52:55], %8, %2\n\t"
      "v_mfma_f32_16x16x32_f16 %3, a[72:75], %8, %3\n\t"
      "v_mfma_f32_16x16x32_f16 %4, a[92:95], %8, %4\n\t"
      "v_mfma_f32_16x16x32_f16 %0, a[16:19], %9, %0\n\t"
      "v_mfma_f32_16x16x32_f16 %1, a[36:39], %9, %1\n\t"
      "v_mfma_f32_16x16x32_f16 %2, a[56:59], %9, %2\n\t"
      "v_mfma_f32_16x16x32_f16 %3, a[76:79], %9, %3\n\t"
      "v_mfma_f32_16x16x32_f16 %4, a[96:99], %9, %4\n\t"
      "s_nop 7\n\t"
      "s_nop 7"
      : "+v"(acc0), "+v"(acc1), "+v"(acc2), "+v"(acc3), "+v"(acc4)
      : "v"(ah0), "v"(ah1), "v"(ah2), "v"(ah3), "v"(ah4));
    __builtin_amdgcn_sched_barrier(0);

    // gates lane-local: acc[r] = gate r (i,f,g,o) of cell j = jb + T*4
    half_t* hwr = hbuf + (p^1)*NB*HSTR + bl*HSTR + jb;
    #define GATE(A, T) { \
      float cn = hsig(A[1])*c_reg[T] + hsig(A[0])*tanh_(A[2]); \
      float hn = hsig(A[3])*tanh_(cn); \
      c_reg[T] = cn; hm_reg[T] = fmaxf(hm_reg[T], hn); \
      hwr[(T)*4] = (half_t)hn; }
    GATE(acc0, 0) GATE(acc1, 1) GATE(acc2, 2) GATE(acc3, 3) GATE(acc4, 4)
    #undef GATE

    #pragma unroll
    for (int T = 0; T < 5; ++T) curp[T] = nA[T];
    #pragma unroll
    for (int T = 0; T < 5; ++T) nA[T] = nB[T];

    // lgkm-only barrier (global prefetch stays in flight); re-clobber a0..a99
    asm volatile("s_waitcnt lgkmcnt(0)" ::: "memory", ACLOBS);
    __builtin_amdgcn_s_barrier();
    __builtin_amdgcn_sched_barrier(0);
    p ^= 1;
  }

  if (!last){
    for (int i = tid; i < NB*HSTR; i += 512) stateH[(size_t)blk*NB*HSTR + i] = hbuf[p*NB*HSTR + i];
    float* sc = stateC + ((size_t)blk*512 + tid)*10;
    #pragma unroll
    for (int T = 0; T < 5; ++T){ sc[T] = c_reg[T]; sc[5+T] = hm_reg[T]; }
  } else {
    #pragma unroll
    for (int T = 0; T < 5; ++T){
      int j = jb + T*4;
      if (j < HID) pooled[(size_t)(b0 + bl)*300 + d*HID + j] = hm_reg[T];
    }
  }
}

// ================= final MLP + softmax =================
__global__ __launch_bounds__(256) void fc(const float* __restrict__ pooled,
                                          const float* __restrict__ w1, const float* __restrict__ b1,
                                          const float* __restrict__ w2, const float* __restrict__ b2,
                                          float* __restrict__ out){
  __shared__ float prow[300];
  __shared__ float ps[64][5];
  __shared__ float z[52];
  __shared__ float lg[12];
  int b = blockIdx.x, tid = threadIdx.x;
  for (int i = tid; i < 300; i += 256) prow[i] = pooled[(size_t)b*300 + i];
  __syncthreads();
  int j = tid & 63, seg = tid >> 6;
  float a = 0.f;
  if (j < 50){
    const float* wr = w1 + (size_t)j*300 + seg*75;
    const float* pr = prow + seg*75;
    #pragma unroll 5
    for (int k = 0; k < 75; ++k) a = fmaf(pr[k], wr[k], a);
  }
  ps[j][seg] = a;
  __syncthreads();
  if (tid < 50) z[tid] = fmaxf(ps[tid][0]+ps[tid][1]+ps[tid][2]+ps[tid][3] + b1[tid], 0.f);
  __syncthreads();
  if (tid < 10){
    float a2 = b2[tid];
    for (int k = 0; k < 50; ++k) a2 = fmaf(z[k], w2[tid*50 + k], a2);
    lg[tid] = a2;
  }
  __syncthreads();
  if (tid < 10){
    float mx = lg[0];
    #pragma unroll
    for (int k = 1; k < 10; ++k) mx = fmaxf(mx, lg[k]);
    float ssum = 0.f;
    #pragma unroll
    for (int k = 0; k < 10; ++k) ssum += __expf(lg[k] - mx);
    out[(size_t)b*10 + tid] = __expf(lg[tid] - mx) / ssum;
  }
}

extern "C" void kernel_launch(void* const* d_in, const int* in_sizes, int n_in,
                              void* d_out, int out_size, void* d_ws, size_t ws_size,
                              hipStream_t stream) {
  const float* x      = (const float*)d_in[0];
  const float* conv_w = (const float*)d_in[1];
  const float* conv_b = (const float*)d_in[2];
  const float* w_ih_f = (const float*)d_in[3];
  const float* w_hh_f = (const float*)d_in[4];
  const float* b_ih_f = (const float*)d_in[5];
  const float* b_hh_f = (const float*)d_in[6];
  const float* w_ih_b = (const float*)d_in[7];
  const float* w_hh_b = (const float*)d_in[8];
  const float* b_ih_b = (const float*)d_in[9];
  const float* b_hh_b = (const float*)d_in[10];
  const float* l1w = (const float*)d_in[11];
  const float* l1b = (const float*)d_in[12];
  const float* l2w = (const float*)d_in[13];
  const float* l2b = (const float*)d_in[14];
  float* out = (float*)d_out;

  char* ws = (char*)d_ws;
  size_t off = 0;
  auto alloc = [&](size_t bytes){ size_t o = off; off += (bytes + 255) & ~(size_t)255; return o; };
  size_t xseq_o = alloc((size_t)BATCH*TSEQ*CH*2);
  size_t preA_o = alloc((size_t)2*PHASE*SLOTSTRIDE*2);
  size_t preB_o = alloc((size_t)2*PHASE*SLOTSTRIDE*2);
  size_t wih_o  = alloc((size_t)2*NPAD*CH*2);
  size_t whh_o  = alloc((size_t)2*NPAD*KPAD*2);
  size_t bs_o   = alloc((size_t)2*NPAD*4);
  size_t pool_o = alloc((size_t)BATCH*300*4);
  size_t stc_o  = alloc((size_t)32*512*10*4);
  size_t sth_o  = alloc((size_t)32*NB*HSTR*2);
  if (off > ws_size){
    fprintf(stderr, "[cnnblstm] WS TOO SMALL: need %zu have %zu\n", off, ws_size);
    return;
  }
  half_t* xseq_p = (half_t*)(ws + xseq_o);
  half_t* preA_p = (half_t*)(ws + preA_o);
  half_t* preB_p = (half_t*)(ws + preB_o);
  half_t* wih_p  = (half_t*)(ws + wih_o);
  half_t* whh_p  = (half_t*)(ws + whh_o);
  float*  bs_p   = (float*)(ws + bs_o);
  float*  pool_p = (float*)(ws + pool_o);
  float*  stc_p  = (float*)(ws + stc_o);
  half_t* sth_p  = (half_t*)(ws + sth_o);

  setup<<<3328 + 640 + 800 + 5, 256, 0, stream>>>(x, conv_w, conv_b,
      w_ih_f, w_hh_f, b_ih_f, b_hh_f, w_ih_b, w_hh_b, b_ih_b, b_hh_b,
      xseq_p, wih_p, whh_p, bs_p);
  // phase-0 proj on the full machine (1048 blocks, small-LDS kernel, 4/CU)
  proj_kernel<<<8*PHASE, 512, 0, stream>>>(xseq_p, wih_p, bs_p, preA_p, 0, PHASE);
  // phase 0: recur(preA) on 32 exclusive CUs, proj phase1 -> preB on the rest
  recur_fused<<<256, 512, 0, stream>>>(preA_p, whh_p, pool_p, stc_p, sth_p,
      1, 0, xseq_p, wih_p, bs_p, preB_p, PHASE, PHASE);
  // phase 1: recur(preB), proj phase2 -> preA
  recur_fused<<<256, 512, 0, stream>>>(preB_p, whh_p, pool_p, stc_p, sth_p,
      0, 0, xseq_p, wih_p, bs_p, preA_p, 2*PHASE, PHASE);
  // phase 2: recur(preA) only
  recur_fused<<<32, 512, 0, stream>>>(preA_p, whh_p, pool_p, stc_p, sth_p,
      0, 1, xseq_p, wih_p, bs_p, preB_p, 0, 0);

  fc<<<BATCH, 256, 0, stream>>>(pool_p, l1w, l1b, l2w, l2b, out);
}

// Round 12
// 751.457 us; speedup vs baseline: 1.0734x; 1.0734x over previous
//
#include <hip/hip_runtime.h>
#include <cstdio>

#define BATCH 256
#define TSEQ  393
#define CH    128
#define FIN   3
#define TIN   800
#define KK    15
#define HID   150
#define NPAD  640      // gate rows: n = nt*16 + kg*4 + g; cell j = 20*wv + 5*kg + T
#define KPAD  160
#define NB    16       // batch rows per recurrence block
#define PHASE 131      // 3 phases x 131 = 393
#define SLOTSTRIDE (160*256*4)  // halves per slot: [(nt,kg)=160][b=256][4]
#define HSTR  170      // h row stride in halves (odd dword stride -> 0 conflicts, R10)

typedef _Float16 half_t;
typedef __attribute__((ext_vector_type(8))) _Float16 h8v;
typedef __attribute__((ext_vector_type(4))) _Float16 h4v;
typedef __attribute__((ext_vector_type(4))) float f4v;

__device__ inline float hsig(float x){
  return __builtin_amdgcn_fmed3f(fmaf(0.2f, x, 0.5f), 0.f, 1.f);
}
__device__ inline float tanh_(float x){
  float e = __expf(2.f*x);
  return fmaf(-2.f, __builtin_amdgcn_rcpf(e + 1.f), 1.f);
}

// row n -> (cell j, gate g):  nt=n>>4, kg=(n>>2)&3, g=n&3, wv=nt/5, T=nt%5,
// j = 20*wv + 5*kg + T  (bijective onto [0,160); j>=150 is padding)
__device__ __host__ inline int row2cell(int n){
  int nt = n >> 4, kg = (n >> 2) & 3, g = n & 3;
  int wv = nt / 5, T = nt - wv*5;
  (void)g;
  return 20*wv + 5*kg + T;
}

// ================= setup: weight prep + conv fused =================
__global__ __launch_bounds__(256) void setup(const float* __restrict__ x,
    const float* __restrict__ conv_w, const float* __restrict__ conv_b,
    const float* __restrict__ wihf, const float* __restrict__ whhf,
    const float* __restrict__ bihf, const float* __restrict__ bhhf,
    const float* __restrict__ wihb, const float* __restrict__ whhb,
    const float* __restrict__ bihb, const float* __restrict__ bhhb,
    half_t* __restrict__ xseq, half_t* __restrict__ wih, half_t* __restrict__ whh,
    float* __restrict__ bsum){
  __shared__ float wl[CH*FIN*KK];
  __shared__ float xl[FIN][78];
  int bx = blockIdx.x, tid = threadIdx.x;
  if (bx < 3328){                       // conv1d+relu+maxpool2 -> xseq f16 [B][T][C]
    int b = bx & 255, t0 = (bx >> 8)*32;
    for (int i = tid; i < CH*FIN*KK; i += 256) wl[i] = conv_w[i];
    int p0 = 2*t0;
    for (int i = tid; i < FIN*78; i += 256){
      int f = i/78, q = i%78; int p = p0 + q;
      xl[f][q] = (p < TIN) ? x[((size_t)b*FIN + f)*TIN + p] : 0.f;
    }
    __syncthreads();
    int c = tid & 127, th = tid >> 7;
    float a0[16], a1[16];
    #pragma unroll
    for (int i=0;i<16;++i){ a0[i]=0.f; a1[i]=0.f; }
    #pragma unroll
    for (int f=0; f<FIN; ++f){
      float xv[46];
      #pragma unroll
      for (int q=0;q<46;++q) xv[q] = xl[f][th*32 + q];
      #pragma unroll
      for (int k=0;k<KK;++k){
        float ws = wl[c*FIN*KK + f*KK + k];
        #pragma unroll
        for (int i=0;i<16;++i){
          a0[i] = fmaf(xv[2*i+k],   ws, a0[i]);
          a1[i] = fmaf(xv[2*i+k+1], ws, a1[i]);
        }
      }
    }
    float bc = conv_b[c];
    #pragma unroll
    for (int i=0;i<16;++i){
      int t = t0 + th*16 + i;
      if (t < TSEQ){
        float v = fmaxf(fmaxf(a0[i], a1[i]) + bc, 0.f);
        xseq[((size_t)b*TSEQ + t)*CH + c] = (half_t)v;
      }
    }
    return;
  }
  bx -= 3328;
  if (bx < 640){                        // W_ih rows n with new cell map
    int i = bx*256 + tid;
    int c = i & 127; int n = (i >> 7) % NPAD; int d = i / (NPAD*CH);
    const float* src = d ? wihb : wihf;
    int j = row2cell(n), g = n & 3;
    float v = (j < HID) ? src[(g*HID + j)*CH + c] : 0.f;
    wih[i] = (half_t)v;
    return;
  }
  bx -= 640;
  if (bx < 800){                        // W_hh rows mapped, cols canonical (= h storage)
    int i = bx*256 + tid;
    int kc = i % KPAD; int n = (i / KPAD) % NPAD; int d = i / (NPAD*KPAD);
    const float* src = d ? whhb : whhf;
    int j = row2cell(n), g = n & 3;
    float v = (j < HID && kc < HID) ? src[(g*HID + j)*HID + kc] : 0.f;
    whh[i] = (half_t)v;
    return;
  }
  { int i = (bx-800)*256 + tid;         // bias sum, mapped
    if (i < 2*NPAD){
      int n = i % NPAD; int d = i / NPAD;
      int j = row2cell(n), g = n & 3;
      float v = 0.f;
      if (j < HID){ int r = g*HID + j; v = d ? (bihb[r] + bhhb[r]) : (bihf[r] + bhhf[r]); }
      bsum[i] = v;
    }
  }
}

// ================= proj body (A=W_ih, B=x) =================
// pre slot layout: h4v for (nt,kg,b) at half-offset ((nt*4+kg)*256 + b)*4
// -> both proj stores and recur loads are 128B-contiguous per kg group.
__device__ __forceinline__ void proj_body(const half_t* __restrict__ xseq,
    const half_t* __restrict__ wih, const float* __restrict__ bsum,
    half_t* __restrict__ pre, int off, int nproj, int idx){
  int bt4 = idx & 3; int rest = idx >> 2;
  int s = rest % nproj; int d = rest / nproj;
  int sg = s + off;
  int t = d ? (TSEQ-1 - sg) : sg;
  int tid = threadIdx.x, wv = tid >> 6, ln = tid & 63;
  int m = ln & 15, kg = ln >> 4;
  half_t* pslot = pre + ((size_t)d*PHASE + s)*SLOTSTRIDE;
  #pragma unroll
  for (int i = 0; i < 5; ++i){
    int nt = wv*5 + i;
    h8v bfr[4];
    #pragma unroll
    for (int ks = 0; ks < 4; ++ks)
      bfr[ks] = *(const h8v*)(wih + ((size_t)d*NPAD + nt*16 + m)*CH + ks*32 + kg*8);
    f4v bs4 = *(const f4v*)(bsum + d*NPAD + nt*16 + kg*4);
    #pragma unroll
    for (int ms = 0; ms < 4; ++ms){
      int b = bt4*64 + ms*16 + m;
      h8v ax[4];
      #pragma unroll
      for (int ks = 0; ks < 4; ++ks)
        ax[ks] = *(const h8v*)(xseq + ((size_t)b*TSEQ + t)*CH + ks*32 + kg*8);
      f4v acc = bs4;
      #pragma unroll
      for (int ks = 0; ks < 4; ++ks)
        acc = __builtin_amdgcn_mfma_f32_16x16x32_f16(bfr[ks], ax[ks], acc, 0, 0, 0);
      h4v hv = {(half_t)acc[0], (half_t)acc[1], (half_t)acc[2], (half_t)acc[3]};
      *(h4v*)(pslot + ((size_t)(nt*4 + kg)*256 + b)*4) = hv;
    }
  }
}

__global__ __launch_bounds__(512) void proj_kernel(const half_t* __restrict__ xseq,
    const half_t* __restrict__ wih, const float* __restrict__ bsum,
    half_t* __restrict__ pre, int off, int nproj){
  proj_body(xseq, wih, bsum, pre, off, nproj, blockIdx.x);
}

// ================= recurrence (intrinsics, big reg budget) =================
// launch_bounds(512,1): 512-VGPR budget -> compiler keeps the 25 W_hh fragments
// resident AND freely interleaves ds_read/MFMA/VALU (R4-R11's hand-asm blocked
// exactly that overlap; per-step time was the SUM of pipe times, not the max).
__global__ __launch_bounds__(512, 1) void recur_fused(
    const half_t* __restrict__ preR, const half_t* __restrict__ whh,
    float* __restrict__ pooled, float* __restrict__ stateC, half_t* __restrict__ stateH,
    int first, int last,
    const half_t* __restrict__ xseq, const half_t* __restrict__ wih,
    const float* __restrict__ bsum, half_t* __restrict__ preW,
    int off_next, int nproj){
  __shared__ __align__(16) half_t hbuf[2*NB*HSTR];   // [2][16 b][170 j]

  if (blockIdx.x >= 32){
    if (nproj > 0) proj_body(xseq, wih, bsum, preW, off_next, nproj, blockIdx.x - 32);
    return;
  }

  int tid = threadIdx.x, wv = tid >> 6, ln = tid & 63;
  int m = ln & 15, kg = ln >> 4;
  int bl = m;
  int bt = blockIdx.x & 15, d = blockIdx.x >> 4;
  int b0 = bt*NB;
  int blk = d*16 + bt;

  // resident W_hh A-fragments (intrinsic path, VGPRs)
  h8v bhh[5][5];
  #pragma unroll
  for (int T = 0; T < 5; ++T)
    #pragma unroll
    for (int ks = 0; ks < 5; ++ks)
      bhh[T][ks] = *(const h8v*)(whh + ((size_t)d*NPAD + (wv*5+T)*16 + m)*KPAD + ks*32 + kg*8);

  int jbase = wv*20 + kg*5;         // lane's cells: jbase + T (contiguous!)

  float c_reg[5], hm_reg[5];
  if (first){
    for (int i = tid; i < 2*NB*HSTR; i += 512) hbuf[i] = (half_t)0.f;
    #pragma unroll
    for (int T = 0; T < 5; ++T){ c_reg[T] = 0.f; hm_reg[T] = -1e30f; }
  } else {
    for (int i = tid; i < NB*HSTR; i += 512) hbuf[i] = stateH[(size_t)blk*NB*HSTR + i];
    for (int i = tid; i < NB*HSTR; i += 512) hbuf[NB*HSTR + i] = (half_t)0.f;
    const float* sc = stateC + ((size_t)blk*512 + tid)*10;
    #pragma unroll
    for (int T = 0; T < 5; ++T){ c_reg[T] = sc[T]; hm_reg[T] = sc[5+T]; }
  }
  __syncthreads();

  const half_t* pb = preR + (size_t)d*PHASE*SLOTSTRIDE;
  int pof = wv*20480 + kg*1024 + (b0 + bl)*4;   // + T*4096

  // depth-2 register prefetch pipeline
  h4v curp[5], nA[5];
  #pragma unroll
  for (int T = 0; T < 5; ++T) curp[T] = *(const h4v*)(pb + pof + T*4096);
  {
    const half_t* p1 = pb + (size_t)SLOTSTRIDE;
    #pragma unroll
    for (int T = 0; T < 5; ++T) nA[T] = *(const h4v*)(p1 + pof + T*4096);
  }

  int p = 0;
  #pragma unroll 1
  for (int s = 0; s < PHASE; ++s){
    int s2 = (s+2 < PHASE) ? s+2 : PHASE-1;
    const half_t* p2 = pb + (size_t)s2*SLOTSTRIDE;
    h4v nB[5];
    #pragma unroll
    for (int T = 0; T < 5; ++T) nB[T] = *(const h4v*)(p2 + pof + T*4096);

    // h B-fragments (same for all waves)
    const half_t* hrd = hbuf + p*NB*HSTR + bl*HSTR;
    h8v ah[5];
    #pragma unroll
    for (int ks = 0; ks < 5; ++ks) ah[ks] = *(const h8v*)(hrd + ks*32 + kg*8);

    // per-tile: MFMA chain then gate math (compiler interleaves T+1 MFMAs
    // with T's VALU gate work -> pipe overlap instead of phase sum)
    half_t* hwr = hbuf + (p^1)*NB*HSTR + bl*HSTR + jbase;
    #pragma unroll
    for (int T = 0; T < 5; ++T){
      f4v a = {(float)curp[T][0], (float)curp[T][1], (float)curp[T][2], (float)curp[T][3]};
      #pragma unroll
      for (int ks = 0; ks < 5; ++ks)
        a = __builtin_amdgcn_mfma_f32_16x16x32_f16(bhh[T][ks], ah[ks], a, 0, 0, 0);
      float cn = hsig(a[1])*c_reg[T] + hsig(a[0])*tanh_(a[2]);
      float hn = hsig(a[3])*tanh_(cn);
      c_reg[T] = cn;
      hm_reg[T] = fmaxf(hm_reg[T], hn);
      hwr[T] = (half_t)hn;
    }

    #pragma unroll
    for (int T = 0; T < 5; ++T) curp[T] = nA[T];
    #pragma unroll
    for (int T = 0; T < 5; ++T) nA[T] = nB[T];

    // lgkm-only barrier: h writes drained; global prefetch stays in flight
    asm volatile("s_waitcnt lgkmcnt(0)" ::: "memory");
    __builtin_amdgcn_s_barrier();
    __builtin_amdgcn_sched_barrier(0);
    p ^= 1;
  }

  if (!last){
    for (int i = tid; i < NB*HSTR; i += 512) stateH[(size_t)blk*NB*HSTR + i] = hbuf[p*NB*HSTR + i];
    float* sc = stateC + ((size_t)blk*512 + tid)*10;
    #pragma unroll
    for (int T = 0; T < 5; ++T){ sc[T] = c_reg[T]; sc[5+T] = hm_reg[T]; }
  } else {
    #pragma unroll
    for (int T = 0; T < 5; ++T){
      int j = jbase + T;
      if (j < HID) pooled[(size_t)(b0 + bl)*300 + d*HID + j] = hm_reg[T];
    }
  }
}

// ================= final MLP + softmax =================
__global__ __launch_bounds__(256) void fc(const float* __restrict__ pooled,
                                          const float* __restrict__ w1, const float* __restrict__ b1,
                                          const float* __restrict__ w2, const float* __restrict__ b2,
                                          float* __restrict__ out){
  __shared__ float prow[300];
  __shared__ float ps[64][5];
  __shared__ float z[52];
  __shared__ float lg[12];
  int b = blockIdx.x, tid = threadIdx.x;
  for (int i = tid; i < 300; i += 256) prow[i] = pooled[(size_t)b*300 + i];
  __syncthreads();
  int j = tid & 63, seg = tid >> 6;
  float a = 0.f;
  if (j < 50){
    const float* wr = w1 + (size_t)j*300 + seg*75;
    const float* pr = prow + seg*75;
    #pragma unroll 5
    for (int k = 0; k < 75; ++k) a = fmaf(pr[k], wr[k], a);
  }
  ps[j][seg] = a;
  __syncthreads();
  if (tid < 50) z[tid] = fmaxf(ps[tid][0]+ps[tid][1]+ps[tid][2]+ps[tid][3] + b1[tid], 0.f);
  __syncthreads();
  if (tid < 10){
    float a2 = b2[tid];
    for (int k = 0; k < 50; ++k) a2 = fmaf(z[k], w2[tid*50 + k], a2);
    lg[tid] = a2;
  }
  __syncthreads();
  if (tid < 10){
    float mx = lg[0];
    #pragma unroll
    for (int k = 1; k < 10; ++k) mx = fmaxf(mx, lg[k]);
    float ssum = 0.f;
    #pragma unroll
    for (int k = 0; k < 10; ++k) ssum += __expf(lg[k] - mx);
    out[(size_t)b*10 + tid] = __expf(lg[tid] - mx) / ssum;
  }
}

extern "C" void kernel_launch(void* const* d_in, const int* in_sizes, int n_in,
                              void* d_out, int out_size, void* d_ws, size_t ws_size,
                              hipStream_t stream) {
  const float* x      = (const float*)d_in[0];
  const float* conv_w = (const float*)d_in[1];
  const float* conv_b = (const float*)d_in[2];
  const float* w_ih_f = (const float*)d_in[3];
  const float* w_hh_f = (const float*)d_in[4];
  const float* b_ih_f = (const float*)d_in[5];
  const float* b_hh_f = (const float*)d_in[6];
  const float* w_ih_b = (const float*)d_in[7];
  const float* w_hh_b = (const float*)d_in[8];
  const float* b_ih_b = (const float*)d_in[9];
  const float* b_hh_b = (const float*)d_in[10];
  const float* l1w = (const float*)d_in[11];
  const float* l1b = (const float*)d_in[12];
  const float* l2w = (const float*)d_in[13];
  const float* l2b = (const float*)d_in[14];
  float* out = (float*)d_out;

  char* ws = (char*)d_ws;
  size_t off = 0;
  auto alloc = [&](size_t bytes){ size_t o = off; off += (bytes + 255) & ~(size_t)255; return o; };
  size_t xseq_o = alloc((size_t)BATCH*TSEQ*CH*2);
  size_t preA_o = alloc((size_t)2*PHASE*SLOTSTRIDE*2);
  size_t preB_o = alloc((size_t)2*PHASE*SLOTSTRIDE*2);
  size_t wih_o  = alloc((size_t)2*NPAD*CH*2);
  size_t whh_o  = alloc((size_t)2*NPAD*KPAD*2);
  size_t bs_o   = alloc((size_t)2*NPAD*4);
  size_t pool_o = alloc((size_t)BATCH*300*4);
  size_t stc_o  = alloc((size_t)32*512*10*4);
  size_t sth_o  = alloc((size_t)32*NB*HSTR*2);
  if (off > ws_size){
    fprintf(stderr, "[cnnblstm] WS TOO SMALL: need %zu have %zu\n", off, ws_size);
    return;
  }
  half_t* xseq_p = (half_t*)(ws + xseq_o);
  half_t* preA_p = (half_t*)(ws + preA_o);
  half_t* preB_p = (half_t*)(ws + preB_o);
  half_t* wih_p  = (half_t*)(ws + wih_o);
  half_t* whh_p  = (half_t*)(ws + whh_o);
  float*  bs_p   = (float*)(ws + bs_o);
  float*  pool_p = (float*)(ws + pool_o);
  float*  stc_p  = (float*)(ws + stc_o);
  half_t* sth_p  = (half_t*)(ws + sth_o);

  int projBlocks = 4*PHASE*2;   // 1048

  setup<<<3328 + 640 + 800 + 5, 256, 0, stream>>>(x, conv_w, conv_b,
      w_ih_f, w_hh_f, b_ih_f, b_hh_f, w_ih_b, w_hh_b, b_ih_b, b_hh_b,
      xseq_p, wih_p, whh_p, bs_p);
  proj_kernel<<<projBlocks, 512, 0, stream>>>(xseq_p, wih_p, bs_p, preA_p, 0, PHASE);
  // phase 0: recur(preA) + one-shot proj blocks phase1 -> preB
  recur_fused<<<32 + projBlocks, 512, 0, stream>>>(preA_p, whh_p, pool_p, stc_p, sth_p,
      1, 0, xseq_p, wih_p, bs_p, preB_p, PHASE, PHASE);
  // phase 1: recur(preB) + proj phase2 -> preA
  recur_fused<<<32 + projBlocks, 512, 0, stream>>>(preB_p, whh_p, pool_p, stc_p, sth_p,
      0, 0, xseq_p, wih_p, bs_p, preA_p, 2*PHASE, PHASE);
  // phase 2: recur(preA) only
  recur_fused<<<32, 512, 0, stream>>>(preA_p, whh_p, pool_p, stc_p, sth_p,
      0, 1, xseq_p, wih_p, bs_p, preB_p, 0, 0);

  fc<<<BATCH, 256, 0, stream>>>(pool_p, l1w, l1b, l2w, l2b, out);
}